// Round 16
// baseline (97.773 us; speedup 1.0000x reference)
//
#include <hip/hip_runtime.h>
#include <hip/hip_fp16.h>

// X: (8, 2048, 256) fp32; W1: (64,8); b1: (64); W2: (2,64); b2: (2)
// patches: p = 0..510, l = 4p..4p+7 ; out: (8, 511, 256, 2) fp32
#define L_DIM 2048
#define C_DIM 256
#define P_CNT 511
#define H_DIM 64

static __device__ __forceinline__ __half2 bc_h2(unsigned u) {
    __half2 h; __builtin_memcpy(&h, &u, 4); return h;
}
static __device__ __forceinline__ unsigned bc_u32(__half2 h) {
    unsigned u; __builtin_memcpy(&u, &h, 4); return u;
}

// Prep: splat each weight into both halves of an f16x2 dword in d_ws.
// Layout per h (stride 12 dwords, 16B aligned):
//   [0..7]=W1[h][0..7], [8]=b1[h], [9]=W2[0][h], [10]=W2[1][h], [11]=0
__global__ void prep_weights(const float* __restrict__ W1,
                             const float* __restrict__ b1,
                             const float* __restrict__ W2,
                             unsigned* __restrict__ ws) {
    const int h = threadIdx.x;
    if (h < H_DIM) {
#pragma unroll
        for (int j = 0; j < 8; ++j)
            ws[h * 12 + j] = bc_u32(__float2half2_rn(W1[h * 8 + j]));
        ws[h * 12 + 8]  = bc_u32(__float2half2_rn(b1[h]));
        ws[h * 12 + 9]  = bc_u32(__float2half2_rn(W2[h]));          // W2[0][h]
        ws[h * 12 + 10] = bc_u32(__float2half2_rn(W2[H_DIM + h]));  // W2[1][h]
        ws[h * 12 + 11] = 0;
    }
}

// thread = (b, channel, 2 patches packed into __half2 lanes)
// All inner-loop math in packed f16: v_pk_fma_f16 is one 2-cyc pass (2x the
// fp32 pk rate); v_exp_f16/v_rcp_f16 keep trans cost equal. Weights arrive
// pre-splatted -> SGPR operands, zero per-iter conversion.
// gelu f16 range check: z = t*(k1+k2*t^2) in [-14.6, +14.6] for |t|<=4.04;
// 2^z stays in f16 finite range; beyond, e->inf -> rcp->0 -> g=0 (correct tail),
// e->0 -> g=t (correct tail).
__global__ __launch_bounds__(256, 8) void offset_predictor_kernel(
    const float* __restrict__ X,
    const unsigned* __restrict__ ws,
    const float* __restrict__ b2,
    float* __restrict__ out)
{
    const int tid   = blockIdx.x * 256 + threadIdx.x;
    const int c     = tid & 255;            // consecutive threads -> consecutive channels
    const int ptile = (tid >> 8) & 255;
    const int b     = tid >> 16;
    const int p0    = ptile * 2;

    // Patch-pair vectors: pv[j] = f16x2(X[4p0+j], X[4p0+4+j]) at channel c.
    const float* xb = X + (size_t)b * (L_DIM * C_DIM) + c;
    __half2 pv[8];
#pragma unroll
    for (int j = 0; j < 8; ++j) {
        int l0 = 4 * p0 + j;                // <= 2047 always
        int l1 = l0 + 4;
        if (l1 > L_DIM - 1) l1 = L_DIM - 1; // only ptile=255's invalid second patch
        pv[j] = __floats2half2_rn(xb[(size_t)l0 * C_DIM], xb[(size_t)l1 * C_DIM]);
    }

    const __half2 K1  = __float2half2_rn(-2.3022038f);   // -1.5957691216*log2e
    const __half2 K2  = __float2half2_rn(-0.10294324f);  // -0.0713548162*log2e
    const __half2 ONE = __float2half2_rn(1.0f);

    __half2 accA = __float2half2_rn(b2[0]);  // (o0 @ p0, o0 @ p0+1)
    __half2 accB = __float2half2_rn(b2[1]);  // (o1 @ p0, o1 @ p0+1)

    const uint4* wsq = (const uint4*)ws;     // wave-uniform -> s_load_dwordx4
#pragma unroll 4
    for (int h = 0; h < H_DIM; ++h) {
        const uint4 q0 = wsq[h * 3 + 0];     // w1[0..3] (f16-splat)
        const uint4 q1 = wsq[h * 3 + 1];     // w1[4..7]
        const uint4 q2 = wsq[h * 3 + 2];     // b1, w2o0, w2o1, pad

        __half2 t = bc_h2(q2.x);             // b1[h]
        t = __hfma2(pv[0], bc_h2(q0.x), t);
        t = __hfma2(pv[1], bc_h2(q0.y), t);
        t = __hfma2(pv[2], bc_h2(q0.z), t);
        t = __hfma2(pv[3], bc_h2(q0.w), t);
        t = __hfma2(pv[4], bc_h2(q1.x), t);
        t = __hfma2(pv[5], bc_h2(q1.y), t);
        t = __hfma2(pv[6], bc_h2(q1.z), t);
        t = __hfma2(pv[7], bc_h2(q1.w), t);

        // f16 tanh-form gelu: g = t * rcp(1 + 2^(t*(K1 + K2*t^2)))
        const __half2 t2  = __hmul2(t, t);
        const __half2 z   = __hmul2(t, __hfma2(t2, K2, K1));
        const __half2 e   = h2exp2(z);                 // 2x v_exp_f16
        const __half2 r   = h2rcp(__hadd2(e, ONE));    // 2x v_rcp_f16
        const __half2 g   = __hmul2(t, r);

        accA = __hfma2(g, bc_h2(q2.y), accA);
        accB = __hfma2(g, bc_h2(q2.z), accB);
    }

    // out[((b*511 + p)*256 + c)*2 + o] : contiguous float2 per thread, coalesced across c
    const float2 fA = __half22float2(accA);  // (o0@p0, o0@p0+1)
    const float2 fB = __half22float2(accB);  // (o1@p0, o1@p0+1)
    float* ob = out + ((size_t)(b * P_CNT) * C_DIM + c) * 2;
    *(float2*)(ob + (size_t)p0 * (C_DIM * 2)) = make_float2(fA.x, fB.x);
    if (p0 + 1 < P_CNT)
        *(float2*)(ob + (size_t)(p0 + 1) * (C_DIM * 2)) = make_float2(fA.y, fB.y);
}

extern "C" void kernel_launch(void* const* d_in, const int* in_sizes, int n_in,
                              void* d_out, int out_size, void* d_ws, size_t ws_size,
                              hipStream_t stream) {
    const float* X  = (const float*)d_in[0];
    const float* W1 = (const float*)d_in[1];
    const float* b1 = (const float*)d_in[2];
    const float* W2 = (const float*)d_in[3];
    const float* b2 = (const float*)d_in[4];
    float* out = (float*)d_out;
    unsigned* ws = (unsigned*)d_ws;          // 64*12 dwords = 3 KB used

    prep_weights<<<1, 64, 0, stream>>>(W1, b1, W2, ws);
    offset_predictor_kernel<<<2048, 256, 0, stream>>>(X, ws, b2, out);
}